// Round 2
// baseline (2421.115 us; speedup 1.0000x reference)
//
#include <hip/hip_runtime.h>
#include <math.h>

typedef long long i64;

#define GWD 1024
#define GMSK 1023
#define GSH 10

__device__ __forceinline__ int nbrs_of(int m, int* nb) {
  int xx = m & GMSK, yy = m >> GSH;
  int c = 0;
  if (xx > 0)    nb[c++] = m - 1;
  if (xx < GMSK) nb[c++] = m + 1;
  if (yy > 0)    nb[c++] = m - GWD;
  if (yy < GMSK) nb[c++] = m + GWD;
  return c;
}

__device__ __forceinline__ int deg_of(int m) {
  int xx = m & GMSK, yy = m >> GSH;
  return (xx > 0) + (xx < GMSK) + (yy > 0) + (yy < GMSK);
}

// ---- level-1 matching: partner1[i] = min-index argmax_j w(i,j), gather only
__global__ void k_match1(const float* __restrict__ x, int* __restrict__ partner1, int n1) {
#pragma clang fp contract(off)
  int i = blockIdx.x * blockDim.x + threadIdx.x;
  if (i >= n1) return;
  float xi = x[(i64)i * 5];
  float invi = 1.0f / (float)deg_of(i);
  int nb[4];
  int cnt = nbrs_of(i, nb);
  float best = -INFINITY;
  int pr = n1;
  for (int t = 0; t < cnt; ++t) {
    int j = nb[t];
    float w = fabsf(xi - x[(i64)j * 5]) * (invi + 1.0f / (float)deg_of(j));
    if (w > best) { best = w; pr = j; }
    else if (w == best && j < pr) pr = j;
  }
  partner1[i] = (pr >= n1) ? i : pr;
}

__global__ void k_cluster1(const int* __restrict__ partner1, int* __restrict__ c1, int n1) {
  int i = blockIdx.x * blockDim.x + threadIdx.x;
  if (i >= n1) return;
  int p = partner1[i];
  c1[i] = (partner1[p] == i) ? min(i, p) : i;
}

// conv1 for one node: relu( mean_nb(x_j) @ W1 + x_m @ W1r + b1 )
__device__ __forceinline__ void conv1_eval(const float* __restrict__ x, int m,
                                           const float* w1, const float* w1r,
                                           const float* b1, float* out) {
  int nb[4];
  int cnt = nbrs_of(m, nb);
  float s[5] = {0.f, 0.f, 0.f, 0.f, 0.f};
  for (int t = 0; t < cnt; ++t) {
    const float* xj = x + (i64)nb[t] * 5;
#pragma unroll
    for (int k = 0; k < 5; ++k) s[k] += xj[k];
  }
  float xm[5];
#pragma unroll
  for (int k = 0; k < 5; ++k) xm[k] = x[(i64)m * 5 + k];
  float cf = (float)cnt;
#pragma unroll
  for (int f = 0; f < 16; ++f) {
    float a = 0.f, rt = 0.f;
#pragma unroll
    for (int k = 0; k < 5; ++k) {
      a  += s[k]  * w1[k * 16 + f];
      rt += xm[k] * w1r[k * 16 + f];
    }
    out[f] = fmaxf(a / cf + rt + b1[f], 0.0f);
  }
}

// ---- pool1 (heads only): xp = max over members of conv1; posp = centroid; deg2 = coarse out-degree
__global__ void k_pool1(const float* __restrict__ x, const float* __restrict__ pos,
                        const int* __restrict__ partner1, const int* __restrict__ c1,
                        const float* __restrict__ W1, const float* __restrict__ W1r,
                        const float* __restrict__ b1,
                        float* __restrict__ xp, float* __restrict__ posp,
                        int* __restrict__ deg2, int n1) {
  __shared__ float w1s[80], w1rs[80], b1s[16];
  for (int t = threadIdx.x; t < 80; t += blockDim.x) { w1s[t] = W1[t]; w1rs[t] = W1r[t]; }
  if (threadIdx.x < 16) b1s[threadIdx.x] = b1[threadIdx.x];
  __syncthreads();
  int i = blockIdx.x * blockDim.x + threadIdx.x;
  if (i >= n1) return;
  if (c1[i] != i) return;  // heads only
  int p = partner1[i];
  bool pair = (p != i) && (partner1[p] == i);

  float v[16];
  conv1_eval(x, i, w1s, w1rs, b1s, v);
  if (pair) {
    float u[16];
    conv1_eval(x, p, w1s, w1rs, b1s, u);
#pragma unroll
    for (int f = 0; f < 16; ++f) v[f] = fmaxf(v[f], u[f]);
  }
#pragma unroll
  for (int f = 0; f < 16; ++f) xp[(i64)i * 16 + f] = v[f];

  float px = pos[(i64)i * 2], py = pos[(i64)i * 2 + 1];
  if (pair) {
    px = (px + pos[(i64)p * 2]) * 0.5f;
    py = (py + pos[(i64)p * 2 + 1]) * 0.5f;
  }
  posp[(i64)i * 2] = px;
  posp[(i64)i * 2 + 1] = py;

  // coarse out-degree (with multiplicity)
  int d = 0;
  int mem[2]; mem[0] = i; mem[1] = p;
  int nm = pair ? 2 : 1;
  for (int t = 0; t < nm; ++t) {
    int nb[4];
    int cn = nbrs_of(mem[t], nb);
    for (int u = 0; u < cn; ++u)
      if (c1[nb[u]] != i) ++d;
  }
  deg2[i] = d;
}

// ---- level-2 matching over coarse edges (heads only)
__global__ void k_match2(const int* __restrict__ partner1, const int* __restrict__ c1,
                         const float* __restrict__ posp, const int* __restrict__ deg2,
                         int* __restrict__ partner2, int n1) {
#pragma clang fp contract(off)
  int i = blockIdx.x * blockDim.x + threadIdx.x;
  if (i >= n1) return;
  if (c1[i] != i) return;
  int p = partner1[i];
  bool pair = (p != i) && (partner1[p] == i);
  float pix = posp[(i64)i * 2], piy = posp[(i64)i * 2 + 1];
  int di = deg2[i];
  float invi = (di > 0) ? 1.0f / (float)di : 0.0f;
  float best = -INFINITY;
  int pr = n1;
  int mem[2]; mem[0] = i; mem[1] = p;
  int nm = pair ? 2 : 1;
  for (int t = 0; t < nm; ++t) {
    int nb[4];
    int cn = nbrs_of(mem[t], nb);
    for (int u = 0; u < cn; ++u) {
      int cu = c1[nb[u]];
      if (cu == i) continue;
      float dx = pix - posp[(i64)cu * 2];
      float dy = piy - posp[(i64)cu * 2 + 1];
      float attr = sqrtf((dx * dx + dy * dy) + 1e-12f);
      int dc = deg2[cu];
      float invc = (dc > 0) ? 1.0f / (float)dc : 0.0f;
      float w = attr * (invi + invc);
      if (w > best) { best = w; pr = cu; }
      else if (w == best && cu < pr) pr = cu;
    }
  }
  partner2[i] = (pr >= n1) ? i : pr;
}

// conv2 for one level-1 head h: relu( mean_extern(xp_cu) @ W2 + xp_h @ W2r + b2 )
__device__ __forceinline__ void conv2_eval(const float* __restrict__ xp,
                                           const int* __restrict__ partner1,
                                           const int* __restrict__ c1, int h,
                                           const float* w2, const float* w2r,
                                           const float* b2, float* out) {
  float s[16];
#pragma unroll
  for (int k = 0; k < 16; ++k) s[k] = 0.f;
  int cnt = 0;
  int p = partner1[h];
  bool pair = (p != h) && (partner1[p] == h);
  int mem[2]; mem[0] = h; mem[1] = p;
  int nm = pair ? 2 : 1;
  for (int t = 0; t < nm; ++t) {
    int nb[4];
    int cn = nbrs_of(mem[t], nb);
    for (int u = 0; u < cn; ++u) {
      int cu = c1[nb[u]];
      if (cu == h) continue;
      ++cnt;
      const float* xq = xp + (i64)cu * 16;
#pragma unroll
      for (int k = 0; k < 16; ++k) s[k] += xq[k];
    }
  }
  const float* xh = xp + (i64)h * 16;
  float cf = (float)max(cnt, 1);
#pragma unroll
  for (int f = 0; f < 32; ++f) {
    float a = 0.f, rt = 0.f;
#pragma unroll
    for (int k = 0; k < 16; ++k) {
      a  += s[k]  * w2[k * 32 + f];
      rt += xh[k] * w2r[k * 32 + f];
    }
    out[f] = fmaxf(a / cf + rt + b2[f], 0.0f);
  }
}

// ---- pool2 + partial reduction: per level-2 head, x3 = max over members of conv2; block-reduce
__global__ void k_pool2reduce(const int* __restrict__ partner1, const int* __restrict__ c1,
                              const int* __restrict__ partner2,
                              const float* __restrict__ xp,
                              const float* __restrict__ W2, const float* __restrict__ W2r,
                              const float* __restrict__ b2,
                              float* __restrict__ partials, int n1) {
  __shared__ float w2s[512], w2rs[512], b2s[32];
  for (int t = threadIdx.x; t < 512; t += blockDim.x) { w2s[t] = W2[t]; w2rs[t] = W2r[t]; }
  if (threadIdx.x < 32) b2s[threadIdx.x] = b2[threadIdx.x];
  __syncthreads();

  int i = blockIdx.x * blockDim.x + threadIdx.x;
  float x3[32];
#pragma unroll
  for (int f = 0; f < 32; ++f) x3[f] = 0.f;
  float flag = 0.f;

  if (i < n1 && c1[i] == i) {
    int p2 = partner2[i];
    bool mut2 = (p2 != i) && (partner2[p2] == i);
    if (!(mut2 && p2 < i)) {  // level-2 head
      conv2_eval(xp, partner1, c1, i, w2s, w2rs, b2s, x3);
      if (mut2) {
        float u[32];
        conv2_eval(xp, partner1, c1, p2, w2s, w2rs, b2s, u);
#pragma unroll
        for (int f = 0; f < 32; ++f) x3[f] = fmaxf(x3[f], u[f]);
      }
      flag = 1.f;
    }
  }

  // deterministic block reduction of 33 values
  __shared__ float sm[4 * 33];
  int lane = threadIdx.x & 63, wv = threadIdx.x >> 6;
#pragma unroll
  for (int f = 0; f < 32; ++f) {
    float v = x3[f];
    for (int o = 32; o > 0; o >>= 1) v += __shfl_down(v, o, 64);
    if (lane == 0) sm[wv * 33 + f] = v;
  }
  {
    float v = flag;
    for (int o = 32; o > 0; o >>= 1) v += __shfl_down(v, o, 64);
    if (lane == 0) sm[wv * 33 + 32] = v;
  }
  __syncthreads();
  if (threadIdx.x < 33) {
    float v = sm[threadIdx.x] + sm[33 + threadIdx.x] + sm[66 + threadIdx.x] + sm[99 + threadIdx.x];
    partials[(i64)threadIdx.x * gridDim.x + blockIdx.x] = v;
  }
}

__global__ void k_final(const float* __restrict__ partials, int NB,
                        const float* __restrict__ lin1w, const float* __restrict__ lin1b,
                        const float* __restrict__ lin2w, const float* __restrict__ lin2b,
                        float* __restrict__ out) {
  // 33 rows x NB cols; rows summed serially (deterministic), then tiny MLP
  __shared__ float tot[33];
  int t = threadIdx.x;
  if (t < 33) {
    const float* p = partials + (i64)t * NB;
    float a = 0.f;
    for (int b = 0; b < NB; ++b) a += p[b];
    tot[t] = a;
  }
  __syncthreads();
  if (t == 0) {
    float cnt = tot[32];
    float pooled[32];
    for (int f = 0; f < 32; ++f) pooled[f] = tot[f] / cnt;
    float h[8];
    for (int j = 0; j < 8; ++j) {
      float a = 0.f;
      for (int k = 0; k < 32; ++k) a += pooled[k] * lin1w[k * 8 + j];
      a += lin1b[j];
      h[j] = a >= 0.f ? a : 0.1f * a;
    }
    for (int m = 0; m < 2; ++m) {
      float a = 0.f;
      for (int j = 0; j < 8; ++j) a += h[j] * lin2w[j * 2 + m];
      out[m] = a + lin2b[m];
    }
  }
}

extern "C" void kernel_launch(void* const* d_in, const int* in_sizes, int n_in,
                              void* d_out, int out_size, void* d_ws, size_t ws_size,
                              hipStream_t stream) {
  const float* x   = (const float*)d_in[0];
  const float* pos = (const float*)d_in[1];
  const float* W1  = (const float*)d_in[3];
  const float* W1r = (const float*)d_in[4];
  const float* b1  = (const float*)d_in[5];
  const float* W2  = (const float*)d_in[6];
  const float* W2r = (const float*)d_in[7];
  const float* b2  = (const float*)d_in[8];
  const float* l1w = (const float*)d_in[9];
  const float* l1b = (const float*)d_in[10];
  const float* l2w = (const float*)d_in[11];
  const float* l2b = (const float*)d_in[12];
  float* out = (float*)d_out;

  const int n = in_sizes[0] / 5;  // 1048576 (1024x1024 grid)
  const int B = 256;
  const int gn = (n + B - 1) / B;  // 4096

  // workspace layout: 16n + 2n floats + 4n ints + 33*gn floats  ~= 93 MB
  float* base = (float*)d_ws;
  i64 off = 0;
  float* xp       = base + off; off += (i64)16 * n;
  float* posp     = base + off; off += (i64)2 * n;
  int*   partner1 = (int*)(base + off); off += n;
  int*   c1       = (int*)(base + off); off += n;
  int*   deg2     = (int*)(base + off); off += n;
  int*   partner2 = (int*)(base + off); off += n;
  float* partials = base + off; off += (i64)33 * gn;
  (void)ws_size; (void)n_in; (void)out_size;

  k_match1<<<gn, B, 0, stream>>>(x, partner1, n);
  k_cluster1<<<gn, B, 0, stream>>>(partner1, c1, n);
  k_pool1<<<gn, B, 0, stream>>>(x, pos, partner1, c1, W1, W1r, b1, xp, posp, deg2, n);
  k_match2<<<gn, B, 0, stream>>>(partner1, c1, posp, deg2, partner2, n);
  k_pool2reduce<<<gn, B, 0, stream>>>(partner1, c1, partner2, xp, W2, W2r, b2, partials, n);
  k_final<<<1, 64, 0, stream>>>(partials, gn, l1w, l1b, l2w, l2b, out);
}